// Round 2
// baseline (1983.453 us; speedup 1.0000x reference)
//
#include <hip/hip_runtime.h>

#define D 64

// ---------------------------------------------------------------------------
// Kernel 1: fused dual GEMM.
//   out  = verts @ w0 + b0      (written straight into d_out)
//   vw1  = verts @ w1 + b1      (workspace, consumed by scatter kernel)
// Lane l of each wave holds column l of both weight matrices in VGPRs.
// A wave processes 16 rows per chunk; row fragments are loaded through a
// wave-uniform pointer so they become scalar (s_load) broadcasts.
// Grid sized so each wave gets exactly one chunk (6252 waves vs 6250 chunks).
// ---------------------------------------------------------------------------
__global__ __launch_bounds__(256, 2) void gemm2_kernel(
    const float* __restrict__ verts,
    const float* __restrict__ w0, const float* __restrict__ b0,
    const float* __restrict__ w1, const float* __restrict__ b1,
    float* __restrict__ out, float* __restrict__ vw1, int nrows)
{
    const int lane = threadIdx.x & 63;
    // readfirstlane so the wave id (and everything derived from it) is SGPR.
    const int wib  = __builtin_amdgcn_readfirstlane((int)(threadIdx.x >> 6));
    const int wpb  = blockDim.x >> 6;
    const int gw   = blockIdx.x * wpb + wib;
    const int nw   = gridDim.x * wpb;

    // Weight columns into registers: w?c[k] = w?[k][lane]. Coalesced across
    // lanes, L2-hot (16 KiB each), done once per wave.
    float w0c[D], w1c[D];
#pragma unroll
    for (int k = 0; k < D; ++k) w0c[k] = w0[k * D + lane];
#pragma unroll
    for (int k = 0; k < D; ++k) w1c[k] = w1[k * D + lane];
    const float bias0 = b0[lane];
    const float bias1 = b1[lane];

    const int nchunks = nrows >> 4;           // 16 rows per chunk
    for (int c = gw; c < nchunks; c += nw) {
        const int rowbase = c << 4;
        const float4* rp = (const float4*)(verts + (size_t)rowbase * D);
        float acc0[16], acc1[16];
#pragma unroll
        for (int r = 0; r < 16; ++r) { acc0[r] = bias0; acc1[r] = bias1; }
#pragma unroll
        for (int r = 0; r < 16; ++r) {
#pragma unroll
            for (int k4 = 0; k4 < 16; ++k4) {
                const float4 f = rp[r * 16 + k4];   // wave-uniform broadcast
                acc0[r] = fmaf(f.x, w0c[k4 * 4 + 0], acc0[r]);
                acc0[r] = fmaf(f.y, w0c[k4 * 4 + 1], acc0[r]);
                acc0[r] = fmaf(f.z, w0c[k4 * 4 + 2], acc0[r]);
                acc0[r] = fmaf(f.w, w0c[k4 * 4 + 3], acc0[r]);
                acc1[r] = fmaf(f.x, w1c[k4 * 4 + 0], acc1[r]);
                acc1[r] = fmaf(f.y, w1c[k4 * 4 + 1], acc1[r]);
                acc1[r] = fmaf(f.z, w1c[k4 * 4 + 2], acc1[r]);
                acc1[r] = fmaf(f.w, w1c[k4 * 4 + 3], acc1[r]);
            }
        }
        float* po = out + (size_t)rowbase * D + lane;   // coalesced stores
        float* pw = vw1 + (size_t)rowbase * D + lane;
#pragma unroll
        for (int r = 0; r < 16; ++r) po[r * D] = acc0[r];
#pragma unroll
        for (int r = 0; r < 16; ++r) pw[r * D] = acc1[r];
    }

    // Tail rows (nrows % 16). V=100000 is divisible by 16, but stay general.
    const int tail_start = (nrows >> 4) << 4;
    if (gw == 0) {
        for (int row = tail_start; row < nrows; ++row) {
            float a0 = bias0, a1 = bias1;
            for (int k = 0; k < D; ++k) {
                const float v = verts[(size_t)row * D + k];
                a0 = fmaf(v, w0c[k], a0);
                a1 = fmaf(v, w1c[k], a1);
            }
            out[(size_t)row * D + lane] = a0;
            vw1[(size_t)row * D + lane] = a1;
        }
    }
}

// ---------------------------------------------------------------------------
// Kernel 2: symmetric edge scatter-add.
//   out[src] += vw1[dst];  out[dst] += vw1[src]   (64 floats each)
// 16 threads per edge, float4 gathers, HW fp32 atomics (unsafeAtomicAdd ->
// global_atomic_add_f32; plain atomicAdd would be a CAS loop without
// -munsafe-fp-atomics).
// ---------------------------------------------------------------------------
__global__ __launch_bounds__(256) void scatter_add_kernel(
    const int* __restrict__ edges, const float* __restrict__ vw1,
    float* __restrict__ out, int nedges)
{
    const int gid = blockIdx.x * blockDim.x + threadIdx.x;
    const int e   = gid >> 4;
    if (e >= nedges) return;
    const int sub = (gid & 15) << 2;          // column offset 0,4,...,60

    const int s = edges[(size_t)e * 2 + 0];   // same addr across the 16-lane
    const int t = edges[(size_t)e * 2 + 1];   // group -> one broadcast req

    const float4 fd = *(const float4*)(vw1 + (size_t)t * D + sub);
    const float4 fs = *(const float4*)(vw1 + (size_t)s * D + sub);

    float* po = out + (size_t)s * D + sub;
    unsafeAtomicAdd(po + 0, fd.x);
    unsafeAtomicAdd(po + 1, fd.y);
    unsafeAtomicAdd(po + 2, fd.z);
    unsafeAtomicAdd(po + 3, fd.w);

    float* pt = out + (size_t)t * D + sub;
    unsafeAtomicAdd(pt + 0, fs.x);
    unsafeAtomicAdd(pt + 1, fs.y);
    unsafeAtomicAdd(pt + 2, fs.z);
    unsafeAtomicAdd(pt + 3, fs.w);
}

extern "C" void kernel_launch(void* const* d_in, const int* in_sizes, int n_in,
                              void* d_out, int out_size, void* d_ws, size_t ws_size,
                              hipStream_t stream)
{
    const float* verts = (const float*)d_in[0];
    const int*   edges = (const int*)d_in[1];   // harness converts ints -> int32
    const float* w0k   = (const float*)d_in[2];
    const float* w0b   = (const float*)d_in[3];
    const float* w1k   = (const float*)d_in[4];
    const float* w1b   = (const float*)d_in[5];
    float* out = (float*)d_out;
    float* vw1 = (float*)d_ws;                  // V*D floats = 25.6 MB scratch

    const int nrows  = in_sizes[0] / D;
    const int nedges = in_sizes[1] / 2;

    // GEMM: one 16-row chunk per wave (6250 chunks -> 1563 blocks x 4 waves).
    const int nchunks = (nrows + 15) / 16;
    const int gblocks = (nchunks + 3) / 4;
    gemm2_kernel<<<gblocks, 256, 0, stream>>>(verts, w0k, w0b, w1k, w1b,
                                              out, vw1, nrows);

    // Scatter: one 16-lane group per edge.
    const long long ngroups = (long long)nedges * 16;
    const int blocks = (int)((ngroups + 255) / 256);
    scatter_add_kernel<<<blocks, 256, 0, stream>>>(edges, vw1, out, nedges);
}

// Round 5
// 1129.698 us; speedup vs baseline: 1.7557x; 1.7557x over previous
//
#include <hip/hip_runtime.h>

#define D 64
#define CAP 64   // adjacency bucket capacity; Poisson(20) => P(deg>64) ~ 1e-17

// ---------------------------------------------------------------------------
// Kernel 0: zero the cursor array (kernel instead of hipMemsetAsync: the
// harness whitelist names only hipMemcpyAsync, so stay unquestionably
// graph-capture-safe).
// ---------------------------------------------------------------------------
__global__ __launch_bounds__(256) void zero_cursor_kernel(int* __restrict__ cursor,
                                                          int n)
{
    const int i = blockIdx.x * blockDim.x + threadIdx.x;
    if (i < n) cursor[i] = 0;
}

// ---------------------------------------------------------------------------
// Kernel 1: fused dual GEMM, LDS-staged.
//   out  = verts @ w0 + b0      (written straight into d_out)
//   vw1  = verts @ w1 + b1      (workspace, consumed by gather kernel)
// Block = 256 threads = 4 waves, processes 64 rows: stage rows into LDS with
// coalesced per-lane float4 loads (high MLP), then each wave computes 16 rows
// with lane l owning output column l; row fragments come from wave-uniform
// ds_read_b128 broadcasts; both weight matrices live in VGPRs (128 regs).
// ---------------------------------------------------------------------------
__global__ __launch_bounds__(256, 2) void gemm2_kernel(
    const float* __restrict__ verts,
    const float* __restrict__ w0, const float* __restrict__ b0,
    const float* __restrict__ w1, const float* __restrict__ b1,
    float* __restrict__ out, float* __restrict__ vw1, int nrows)
{
    __shared__ float tile[64][D];        // 16 KiB
    const int tid  = threadIdx.x;
    const int lane = tid & 63;
    const int wid  = tid >> 6;           // 0..3
    const int base = blockIdx.x * 64;
    if (base >= nrows) return;

    // Weight columns into registers: w?c[k] = w?[k][lane]. Coalesced, L2-hot.
    float w0c[D], w1c[D];
#pragma unroll
    for (int k = 0; k < D; ++k) w0c[k] = w0[k * D + lane];
#pragma unroll
    for (int k = 0; k < D; ++k) w1c[k] = w1[k * D + lane];
    const float bias0 = b0[lane];
    const float bias1 = b1[lane];

    // Stage up to 64 rows (rows*16 float4s), coalesced, all independent.
    int rows = nrows - base; if (rows > 64) rows = 64;
    {
        const float4* src = (const float4*)(verts + (size_t)base * D);
        float4* dst = (float4*)(&tile[0][0]);
        for (int j = tid; j < rows * (D / 4); j += 256) dst[j] = src[j];
    }
    __syncthreads();

    const int r0 = wid * 16;             // this wave's 16 rows
    float acc0[16], acc1[16];
#pragma unroll
    for (int r = 0; r < 16; ++r) { acc0[r] = bias0; acc1[r] = bias1; }

#pragma unroll
    for (int r = 0; r < 16; ++r) {
#pragma unroll
        for (int k4 = 0; k4 < D / 4; ++k4) {
            // wave-uniform address -> conflict-free LDS broadcast
            const float4 f = *(const float4*)(&tile[r0 + r][k4 * 4]);
            acc0[r] = fmaf(f.x, w0c[k4 * 4 + 0], acc0[r]);
            acc0[r] = fmaf(f.y, w0c[k4 * 4 + 1], acc0[r]);
            acc0[r] = fmaf(f.z, w0c[k4 * 4 + 2], acc0[r]);
            acc0[r] = fmaf(f.w, w0c[k4 * 4 + 3], acc0[r]);
            acc1[r] = fmaf(f.x, w1c[k4 * 4 + 0], acc1[r]);
            acc1[r] = fmaf(f.y, w1c[k4 * 4 + 1], acc1[r]);
            acc1[r] = fmaf(f.z, w1c[k4 * 4 + 2], acc1[r]);
            acc1[r] = fmaf(f.w, w1c[k4 * 4 + 3], acc1[r]);
        }
    }

#pragma unroll
    for (int r = 0; r < 16; ++r) {
        const int row = base + r0 + r;
        if (row < nrows) {
            out[(size_t)row * D + lane] = acc0[r];
            vw1[(size_t)row * D + lane] = acc1[r];
        }
    }
}

// ---------------------------------------------------------------------------
// Kernel 2: bucket neighbor IDs into fixed-capacity per-vertex lists.
// 2M int atomics on a 400 KB cursor array (vs 128M fp32 atomics before).
// Overflow (statistically impossible here, but correct for any input) falls
// back to direct fp32 atomics into out.
// ---------------------------------------------------------------------------
__global__ __launch_bounds__(256) void build_adj_kernel(
    const int* __restrict__ edges, int* __restrict__ cursor,
    int* __restrict__ adj, const float* __restrict__ vw1,
    float* __restrict__ out, int nedges)
{
    const int e = blockIdx.x * blockDim.x + threadIdx.x;
    if (e >= nedges) return;
    const int s = edges[(size_t)e * 2 + 0];
    const int t = edges[(size_t)e * 2 + 1];

    const int ps = atomicAdd(&cursor[s], 1);
    if (ps < CAP) {
        adj[(size_t)s * CAP + ps] = t;
    } else {
        const float* src = vw1 + (size_t)t * D;
        float* dst = out + (size_t)s * D;
        for (int k = 0; k < D; ++k) unsafeAtomicAdd(dst + k, src[k]);
    }

    const int pt = atomicAdd(&cursor[t], 1);
    if (pt < CAP) {
        adj[(size_t)t * CAP + pt] = s;
    } else {
        const float* src = vw1 + (size_t)s * D;
        float* dst = out + (size_t)t * D;
        for (int k = 0; k < D; ++k) unsafeAtomicAdd(dst + k, src[k]);
    }
}

// ---------------------------------------------------------------------------
// Kernel 3: pull-gather. One 16-lane group per vertex; lane owns 4 columns.
// Neighbor IDs read as int4 (4 gathers in flight per group); accumulation and
// the final out += acc are atomic-free (each vertex owned by one group).
// ---------------------------------------------------------------------------
__global__ __launch_bounds__(256) void gather_kernel(
    const int* __restrict__ cursor, const int* __restrict__ adj,
    const float* __restrict__ vw1, float* __restrict__ out, int nverts)
{
    const int gid = blockIdx.x * blockDim.x + threadIdx.x;
    const int v   = gid >> 4;
    if (v >= nverts) return;
    const int sub = (gid & 15) << 2;

    int deg = cursor[v]; if (deg > CAP) deg = CAP;
    const int* nb = adj + (size_t)v * CAP;

    float4 acc = make_float4(0.f, 0.f, 0.f, 0.f);
    int i = 0;
    for (; i + 4 <= deg; i += 4) {
        const int4 u4 = *(const int4*)(nb + i);   // 16B-aligned (CAP%4==0)
        const float4 f0 = *(const float4*)(vw1 + (size_t)u4.x * D + sub);
        const float4 f1 = *(const float4*)(vw1 + (size_t)u4.y * D + sub);
        const float4 f2 = *(const float4*)(vw1 + (size_t)u4.z * D + sub);
        const float4 f3 = *(const float4*)(vw1 + (size_t)u4.w * D + sub);
        acc.x += f0.x + f1.x + f2.x + f3.x;
        acc.y += f0.y + f1.y + f2.y + f3.y;
        acc.z += f0.z + f1.z + f2.z + f3.z;
        acc.w += f0.w + f1.w + f2.w + f3.w;
    }
    for (; i < deg; ++i) {
        const int u = nb[i];
        const float4 f = *(const float4*)(vw1 + (size_t)u * D + sub);
        acc.x += f.x; acc.y += f.y; acc.z += f.z; acc.w += f.w;
    }

    float4* po = (float4*)(out + (size_t)v * D + sub);
    float4 o = *po;
    o.x += acc.x; o.y += acc.y; o.z += acc.z; o.w += acc.w;
    *po = o;
}

// ---------------------------------------------------------------------------
// Fallback (ws too small): round-2's proven atomic scatter.
// ---------------------------------------------------------------------------
__global__ __launch_bounds__(256) void scatter_add_kernel(
    const int* __restrict__ edges, const float* __restrict__ vw1,
    float* __restrict__ out, int nedges)
{
    const int gid = blockIdx.x * blockDim.x + threadIdx.x;
    const int e   = gid >> 4;
    if (e >= nedges) return;
    const int sub = (gid & 15) << 2;
    const int s = edges[(size_t)e * 2 + 0];
    const int t = edges[(size_t)e * 2 + 1];
    const float4 fd = *(const float4*)(vw1 + (size_t)t * D + sub);
    const float4 fs = *(const float4*)(vw1 + (size_t)s * D + sub);
    float* po = out + (size_t)s * D + sub;
    unsafeAtomicAdd(po + 0, fd.x); unsafeAtomicAdd(po + 1, fd.y);
    unsafeAtomicAdd(po + 2, fd.z); unsafeAtomicAdd(po + 3, fd.w);
    float* pt = out + (size_t)t * D + sub;
    unsafeAtomicAdd(pt + 0, fs.x); unsafeAtomicAdd(pt + 1, fs.y);
    unsafeAtomicAdd(pt + 2, fs.z); unsafeAtomicAdd(pt + 3, fs.w);
}

extern "C" void kernel_launch(void* const* d_in, const int* in_sizes, int n_in,
                              void* d_out, int out_size, void* d_ws, size_t ws_size,
                              hipStream_t stream)
{
    const float* verts = (const float*)d_in[0];
    const int*   edges = (const int*)d_in[1];
    const float* w0k   = (const float*)d_in[2];
    const float* w0b   = (const float*)d_in[3];
    const float* w1k   = (const float*)d_in[4];
    const float* w1b   = (const float*)d_in[5];
    float* out = (float*)d_out;

    const int nrows  = in_sizes[0] / D;
    const int nedges = in_sizes[1] / 2;

    // Workspace layout: vw1 | cursor | adj
    const size_t vw1_bytes    = (size_t)nrows * D * sizeof(float);
    const size_t cursor_bytes = (size_t)nrows * sizeof(int);
    const size_t adj_bytes    = (size_t)nrows * CAP * sizeof(int);
    float* vw1  = (float*)d_ws;
    int* cursor = (int*)((char*)d_ws + vw1_bytes);
    int* adj    = (int*)((char*)d_ws + vw1_bytes + cursor_bytes);
    const bool csr_ok = ws_size >= vw1_bytes + cursor_bytes + adj_bytes;

    // GEMM: 64 rows per 256-thread block.
    const int gblocks = (nrows + 63) / 64;
    gemm2_kernel<<<gblocks, 256, 0, stream>>>(verts, w0k, w0b, w1k, w1b,
                                              out, vw1, nrows);

    if (csr_ok) {
        const int zblocks = (nrows + 255) / 256;
        zero_cursor_kernel<<<zblocks, 256, 0, stream>>>(cursor, nrows);
        const int bblocks = (nedges + 255) / 256;
        build_adj_kernel<<<bblocks, 256, 0, stream>>>(edges, cursor, adj,
                                                      vw1, out, nedges);
        const long long ngroups = (long long)nrows * 16;
        const int vblocks = (int)((ngroups + 255) / 256);
        gather_kernel<<<vblocks, 256, 0, stream>>>(cursor, adj, vw1, out, nrows);
    } else {
        const long long ngroups = (long long)nedges * 16;
        const int blocks = (int)((ngroups + 255) / 256);
        scatter_add_kernel<<<blocks, 256, 0, stream>>>(edges, vw1, out, nedges);
    }
}